// Round 9
// baseline (340.622 us; speedup 1.0000x reference)
//
#include <hip/hip_runtime.h>

// Correlation: out[b, di*9+dj, h, w] = (1/64) * sum_c x1[b,c,h,w] * x2p[b,c,h+di,w+dj]
// x2p = x2 zero-padded by 4 each side. B=8, C=64, H=W=192.
//
// v8 — NO LDS, NO barriers, NO staging. v1..v7 post-mortem: three structurally
// different chunked-LDS pipelines (56/40/30KB, 9/9/3-wave blocks) all sit at
// 150-170us with every pipe at 15-20% and ~5 waves/CU effective residency — the
// per-chunk vmcnt(0)-drain + barrier critical path is the invariant bottleneck.
// v8 deletes it:
//  - Each thread's x2 window is ONE row, 16 consecutive aligned floats (row = h+di-4
//    fixed per thread; dj only slides within the 16). Load 4x f4 (x2) + 2x f4 (x1)
//    per channel straight from global (L1/L2 serve the reuse: 9.4MB/image slab,
//    FETCH was 81MB with LDS anyway), then 72 reg FMAs. Waves fully independent.
//  - Pad handling is free: each output (p,dj) uses exactly one x2 value, so a pad
//    x2 value means that OUTPUT is exactly 0. All addresses are clamped in-bounds
//    (garbage loads where pad), and the epilogue zeroes affected outputs via a
//    per-component scale select (72 selects once, not per channel).
//  - Work unit = (image b, 32x16 tile, di): 5184 waves. Block = 4 consecutive units
//    of one image (di k..k+3 of a tile -> 19 shared x2 rows in L1; identical x1 tile).
//    blockIdx&7 = image -> XCD L2 affinity. Grid 1296 x 256.
//  - VGPR ~112 (acc 72 + win 16 + av 8 + offsets) under launch_bounds(256,2) cap 128
//    -> 4 waves/SIMD resident with NOTHING to wait on but memory; compiler pipelines
//    plain global loads with counted vmcnt (its default), unroll-4 gives lookahead.
//  - Spill canary: WRITE_SIZE must stay 93312 KB.

constexpr int MAXD = 4;
constexpr int OD   = 9;
constexpr int ND   = 81;
constexpr int TB_W = 32;   // tile width
constexpr int TB_H = 16;   // tile height
constexpr int TWp  = 8;    // pixels per thread along w
constexpr int NT   = 256;  // 4 independent waves per block

constexpr int Bc = 8, Cc = 64, Hc = 192, Wc = 192;
constexpr int HW = Hc * Wc;
constexpr int GX = Wc / TB_W;        // 6
constexpr int GY = Hc / TB_H;        // 12
constexpr int NTILE = GX * GY;       // 72
constexpr int UPI   = NTILE * OD;    // 648 units (tile,di) per image
constexpr int NBLK  = Bc * UPI / 4;  // 1296 blocks

__global__ __launch_bounds__(NT, 2) void corr_kernel(
    const float* __restrict__ x1, const float* __restrict__ x2,
    float* __restrict__ out)
{
    const int tid  = threadIdx.x;
    const int lane = tid & 63;
    const int wid  = tid >> 6;         // 0..3: unit within block
    const int px8  = (lane & 3) * 8;   // 0,8,16,24
    const int gh   = lane >> 2;        // 0..15

    // block -> (image, 4 consecutive (tile,di) units). b uniform per block.
    const int B    = blockIdx.x;
    const int b    = B & 7;                  // image == XCD affinity
    const int up   = (B >> 3) * 4 + wid;     // 0..647
    const int di   = up % OD;
    const int tile = up / OD;                // 0..71
    const int ty   = tile / GX;
    const int tx   = tile - ty * GX;
    const int w0   = tx * TB_W;
    const int h0   = ty * TB_H;

    const float* x1b = x1 + (long)b * Cc * HW;
    const float* x2b = x2 + (long)b * Cc * HW;

    // fixed per-thread geometry
    const int r1 = h0 + gh;                       // x1/out row (always valid)
    const int cb = w0 + px8;                      // own col base, f4-aligned
    const int rg = r1 + di - MAXD;                // x2 row (may be pad)
    const bool rowok = (unsigned)rg < (unsigned)Hc;
    const int rgc = min(max(rg, 0), Hc - 1);      // clamped (garbage if pad)
    const int cc0 = (cb >= 4) ? (cb - 4) : 0;             // win chunk0 col (clamped)
    const int cc3 = (cb <= Wc - 12) ? (cb + 8) : (Wc - 4);// win chunk3 col (clamped)

    // channel-0 float offsets within the image (all in-bounds by construction)
    const int o1 = r1  * Wc + cb;        // x1: 2 f4
    const int e0 = rgc * Wc + cc0;       // x2 win[0..3]
    const int e1 = rgc * Wc + cb;        // x2 win[4..7]; +4 -> win[8..11]
    const int e3 = rgc * Wc + cc3;       // x2 win[12..15]

    float acc[OD][TWp];
#pragma unroll
    for (int dj = 0; dj < OD; ++dj)
#pragma unroll
        for (int p = 0; p < TWp; ++p) acc[dj][p] = 0.f;

    // ---- main loop: 6 global f4 loads -> 72 FMAs per channel; no sync anywhere ----
#pragma unroll 4
    for (int c = 0; c < Cc; ++c) {
        const float* p1 = x1b + c * HW;
        const float* p2 = x2b + c * HW;
        float4 a0 = *(const float4*)(p1 + o1);
        float4 a1 = *(const float4*)(p1 + o1 + 4);
        float4 q0 = *(const float4*)(p2 + e0);
        float4 q1 = *(const float4*)(p2 + e1);
        float4 q2 = *(const float4*)(p2 + e1 + 4);
        float4 q3 = *(const float4*)(p2 + e3);
        float wn[16] = {q0.x,q0.y,q0.z,q0.w,  q1.x,q1.y,q1.z,q1.w,
                        q2.x,q2.y,q2.z,q2.w,  q3.x,q3.y,q3.z,q3.w};
        float av[8]  = {a0.x,a0.y,a0.z,a0.w,  a1.x,a1.y,a1.z,a1.w};
#pragma unroll
        for (int dj = 0; dj < OD; ++dj)
#pragma unroll
            for (int p = 0; p < TWp; ++p)
                acc[dj][p] = fmaf(av[p], wn[p + dj], acc[dj][p]);
    }

    // ---- epilogue: zero pad-touched outputs via scale select, store 9 x 2 f4 ----
    const float sc = 1.0f / 64.0f;
    float* ob = out + (((long)b * ND + di * OD) * Hc + r1) * Wc + cb;
#pragma unroll
    for (int dj = 0; dj < OD; ++dj) {
        float v[TWp];
#pragma unroll
        for (int p = 0; p < TWp; ++p) {
            // output (p,dj) uses x2 col cb+p+dj-4, row rg: pad -> exact 0
            const bool ok = rowok && ((unsigned)(cb + p + dj - MAXD) < (unsigned)Wc);
            v[p] = ok ? acc[dj][p] * sc : 0.f;
        }
        float4 v0 = {v[0], v[1], v[2], v[3]};
        float4 v1 = {v[4], v[5], v[6], v[7]};
        *(float4*)(ob + (long)dj * HW)     = v0;
        *(float4*)(ob + (long)dj * HW + 4) = v1;
    }
}

extern "C" void kernel_launch(void* const* d_in, const int* in_sizes, int n_in,
                              void* d_out, int out_size, void* d_ws, size_t ws_size,
                              hipStream_t stream) {
    const float* x1 = (const float*)d_in[0];
    const float* x2 = (const float*)d_in[1];
    float* out = (float*)d_out;
    corr_kernel<<<dim3(NBLK), NT, 0, stream>>>(x1, x2, out);
}

// Round 10
// 335.930 us; speedup vs baseline: 1.0140x; 1.0140x over previous
//
#include <hip/hip_runtime.h>

// Correlation: out[b, di*9+dj, h, w] = (1/64) * sum_c x1[b,c,h,w] * x2p[b,c,h+di,w+dj]
// x2p = x2 zero-padded by 4 each side. B=8, C=64, H=W=192.
//
// v9 = v8 (no-LDS/no-barrier skeleton, verified correct) + forced MLP:
//  - v8's failure: compiler's occupancy heuristic allocated 64 VGPRs (targeting 8
//    waves/SIMD) despite cap 128, leaving zero lookahead -> per-channel L2/L3 latency
//    (~400-700cy) fully exposed -> 211us with VALU 23%, BW 10%, occ 32%.
//  - amdgpu_waves_per_eu(2,3): min 2 = hard cap 256 VGPR; max 3 = allocator targets
//    3 waves/SIMD (~170 regs) instead of sandbagging to 64. This is the knob that
//    overrode-by-heuristic defeated v6 (cap 64) and v8 (chose 64 under cap 128).
//  - Explicit 3-bank channel pipeline (static names only, no runtime-indexed arrays):
//    steady state FMA(bank) -> reload bank for c+3. ~2 channels of loads in flight,
//    432 FMA-cycles between load and use. Demand ~162 regs -> 3 waves/SIMD, 12/CU.
//  - Everything else identical to v8: thread = (image, 32x16 tile, di, 8px); x2 window
//    = one row, 4 aligned f4 (clamped addresses; pad-touched OUTPUTS zeroed once in
//    epilogue via scale-select); block = 4 consecutive di of one tile, one image;
//    blockIdx&7 = image (XCD L2 affinity); grid 1296 x 256.
//  - Canaries: VGPR_Count must be ~140-170 (64 again = null, next is asm fencing);
//    WRITE_SIZE must stay 93312 KB (jump = bank-3 spilled -> drop to 2 banks).

constexpr int MAXD = 4;
constexpr int OD   = 9;
constexpr int ND   = 81;
constexpr int TB_W = 32;   // tile width
constexpr int TB_H = 16;   // tile height
constexpr int TWp  = 8;    // pixels per thread along w
constexpr int NT   = 256;  // 4 independent waves per block

constexpr int Bc = 8, Cc = 64, Hc = 192, Wc = 192;
constexpr int HW = Hc * Wc;
constexpr int GX = Wc / TB_W;        // 6
constexpr int GY = Hc / TB_H;        // 12
constexpr int NTILE = GX * GY;       // 72
constexpr int UPI   = NTILE * OD;    // 648 units (tile,di) per image
constexpr int NBLK  = Bc * UPI / 4;  // 1296 blocks

struct Bank { float4 a0, a1, q0, q1, q2, q3; };   // one channel: 2x x1 f4 + 4x x2 f4

__global__ __launch_bounds__(NT)
__attribute__((amdgpu_waves_per_eu(2, 3)))
void corr_kernel(const float* __restrict__ x1, const float* __restrict__ x2,
                 float* __restrict__ out)
{
    const int tid  = threadIdx.x;
    const int lane = tid & 63;
    const int wid  = tid >> 6;         // 0..3: unit within block
    const int px8  = (lane & 3) * 8;   // 0,8,16,24
    const int gh   = lane >> 2;        // 0..15

    // block -> (image, 4 consecutive (tile,di) units). b uniform per block.
    const int B    = blockIdx.x;
    const int b    = B & 7;                  // image == XCD affinity
    const int up   = (B >> 3) * 4 + wid;     // 0..647
    const int di   = up % OD;
    const int tile = up / OD;                // 0..71
    const int ty   = tile / GX;
    const int tx   = tile - ty * GX;
    const int w0   = tx * TB_W;
    const int h0   = ty * TB_H;

    const float* x1b = x1 + (long)b * Cc * HW;
    const float* x2b = x2 + (long)b * Cc * HW;

    // fixed per-thread geometry
    const int r1 = h0 + gh;                       // x1/out row (always valid)
    const int cb = w0 + px8;                      // own col base, f4-aligned
    const int rg = r1 + di - MAXD;                // x2 row (may be pad)
    const bool rowok = (unsigned)rg < (unsigned)Hc;
    const int rgc = min(max(rg, 0), Hc - 1);      // clamped (garbage if pad)
    const int cc0 = (cb >= 4) ? (cb - 4) : 0;             // win chunk0 col (clamped)
    const int cc3 = (cb <= Wc - 12) ? (cb + 8) : (Wc - 4);// win chunk3 col (clamped)

    // rolling channel pointers (advance by HW after each channel's loads)
    const float* pa  = x1b + (r1  * Wc + cb);     // x1: 2 f4
    const float* pb0 = x2b + (rgc * Wc + cc0);    // x2 win[0..3]
    const float* pb1 = x2b + (rgc * Wc + cb);     // x2 win[4..7], +4 -> win[8..11]
    const float* pb3 = x2b + (rgc * Wc + cc3);    // x2 win[12..15]

    float acc[OD][TWp];
#pragma unroll
    for (int dj = 0; dj < OD; ++dj)
#pragma unroll
        for (int p = 0; p < TWp; ++p) acc[dj][p] = 0.f;

    auto LOAD = [&](Bank& bk) {
        bk.a0 = *(const float4*)(pa);
        bk.a1 = *(const float4*)(pa + 4);
        bk.q0 = *(const float4*)(pb0);
        bk.q1 = *(const float4*)(pb1);
        bk.q2 = *(const float4*)(pb1 + 4);
        bk.q3 = *(const float4*)(pb3);
        pa += HW; pb0 += HW; pb1 += HW; pb3 += HW;
    };

    auto FMA = [&](const Bank& bk) {
        float wn[16] = {bk.q0.x, bk.q0.y, bk.q0.z, bk.q0.w,
                        bk.q1.x, bk.q1.y, bk.q1.z, bk.q1.w,
                        bk.q2.x, bk.q2.y, bk.q2.z, bk.q2.w,
                        bk.q3.x, bk.q3.y, bk.q3.z, bk.q3.w};
        float av[8]  = {bk.a0.x, bk.a0.y, bk.a0.z, bk.a0.w,
                        bk.a1.x, bk.a1.y, bk.a1.z, bk.a1.w};
#pragma unroll
        for (int dj = 0; dj < OD; ++dj)
#pragma unroll
            for (int p = 0; p < TWp; ++p)
                acc[dj][p] = fmaf(av[p], wn[p + dj], acc[dj][p]);
    };

    // ---- 3-bank rotating pipeline over 64 channels; no sync anywhere ----
    Bank A, Bb, Cb;
    LOAD(A); LOAD(Bb); LOAD(Cb);          // c = 0,1,2
#pragma unroll 1
    for (int t = 0; t < 20; ++t) {        // consumes c=3t..3t+2, loads c=3t+3..3t+5
        FMA(A);  LOAD(A);
        FMA(Bb); LOAD(Bb);
        FMA(Cb); LOAD(Cb);
    }
    FMA(A); LOAD(A);                      // consume c=60, load c=63
    FMA(Bb);                              // c=61
    FMA(Cb);                              // c=62
    FMA(A);                               // c=63

    // ---- epilogue: zero pad-touched outputs via scale select, store 9 x 2 f4 ----
    const float sc = 1.0f / 64.0f;
    float* ob = out + (((long)b * ND + di * OD) * Hc + r1) * Wc + cb;
#pragma unroll
    for (int dj = 0; dj < OD; ++dj) {
        float v[TWp];
#pragma unroll
        for (int p = 0; p < TWp; ++p) {
            // output (p,dj) uses x2 col cb+p+dj-4, row rg: pad -> exact 0
            const bool ok = rowok && ((unsigned)(cb + p + dj - MAXD) < (unsigned)Wc);
            v[p] = ok ? acc[dj][p] * sc : 0.f;
        }
        float4 v0 = {v[0], v[1], v[2], v[3]};
        float4 v1 = {v[4], v[5], v[6], v[7]};
        *(float4*)(ob + (long)dj * HW)     = v0;
        *(float4*)(ob + (long)dj * HW + 4) = v1;
    }
}

extern "C" void kernel_launch(void* const* d_in, const int* in_sizes, int n_in,
                              void* d_out, int out_size, void* d_ws, size_t ws_size,
                              hipStream_t stream) {
    const float* x1 = (const float*)d_in[0];
    const float* x2 = (const float*)d_in[1];
    float* out = (float*)d_out;
    corr_kernel<<<dim3(NBLK), NT, 0, stream>>>(x1, x2, out);
}